// Round 1
// baseline (3411.192 us; speedup 1.0000x reference)
//
#include <hip/hip_runtime.h>
#include <math.h>

#define N_AUTHOR 200000
#define N_SUBJECT 50000
#define N_PAPER 100000
#define NEDGE 1000000
#define D 64
#define NEG_SLOPE 0.01f

// ---------- helpers ----------

__device__ __forceinline__ unsigned enc_f32(float f) {
    unsigned b = __float_as_uint(f);
    return (b & 0x80000000u) ? ~b : (b | 0x80000000u);
}
__device__ __forceinline__ float dec_f32(unsigned e) {
    unsigned b = (e & 0x80000000u) ? (e ^ 0x80000000u) : ~e;
    return __uint_as_float(b);
}

// ---------- kernels ----------

// out[row] = dot(feat[row, :], vec)   (wave per row, lane per feature)
__global__ void dot_rows_kernel(const float* __restrict__ feat,
                                const float* __restrict__ vec,
                                float* __restrict__ out, int n) {
    int row  = blockIdx.x * 4 + (threadIdx.x >> 6);
    int lane = threadIdx.x & 63;
    if (row >= n) return;
    float v = feat[row * D + lane] * vec[lane];
#pragma unroll
    for (int o = 32; o > 0; o >>= 1) v += __shfl_xor(v, o, 64);
    if (lane == 0) out[row] = v;
}

// segment-max of leakyrelu(el[src]+er[dst]) by dst, via encoded atomicMax
__global__ void edge_max_kernel(const int* __restrict__ src,
                                const int* __restrict__ dst,
                                const float* __restrict__ el,
                                const float* __restrict__ er,
                                unsigned* __restrict__ emax) {
    int i = blockIdx.x * blockDim.x + threadIdx.x;
    if (i >= NEDGE) return;
    int d = dst[i];
    float e = el[src[i]] + er[d];
    e = e > 0.0f ? e : NEG_SLOPE * e;
    atomicMax(&emax[d], enc_f32(e));
}

// ee = exp(e - emax[dst]); denom[dst] += ee; store ee
__global__ void edge_expsum_kernel(const int* __restrict__ src,
                                   const int* __restrict__ dst,
                                   const float* __restrict__ el,
                                   const float* __restrict__ er,
                                   const unsigned* __restrict__ emax,
                                   float* __restrict__ ee,
                                   float* __restrict__ denom) {
    int i = blockIdx.x * blockDim.x + threadIdx.x;
    if (i >= NEDGE) return;
    int d = dst[i];
    float e = el[src[i]] + er[d];
    e = e > 0.0f ? e : NEG_SLOPE * e;
    float m = dec_f32(emax[d]);
    float x = expf(e - m);
    ee[i] = x;
    atomicAdd(&denom[d], x);
}

// wave per edge: accum[dst, :] += (ee/denom[dst]) * feat_src[src, :]
__global__ void edge_aggregate_kernel(const int* __restrict__ src,
                                      const int* __restrict__ dst,
                                      const float* __restrict__ feat_src,
                                      const float* __restrict__ ee,
                                      const float* __restrict__ denom,
                                      float* __restrict__ accum) {
    int e    = blockIdx.x * 4 + (threadIdx.x >> 6);
    int lane = threadIdx.x & 63;
    if (e >= NEDGE) return;
    int s = src[e], d = dst[e];
    float a = ee[e] / denom[d];
    atomicAdd(&accum[d * D + lane], a * feat_src[s * D + lane]);
}

// wave per node: h = elu(accum) in-place; wsum[m] += tanh(h @ fc_w.T + fc_b) @ sem_attn
__global__ void elu_semantic_kernel(float* __restrict__ h,
                                    const float* __restrict__ fc_w,
                                    const float* __restrict__ fc_b,
                                    const float* __restrict__ sem_attn,
                                    float* __restrict__ wsum,
                                    int m_index, int n) {
    int node = blockIdx.x * 4 + (threadIdx.x >> 6);
    int lane = threadIdx.x & 63;
    if (node >= n) return;
    float x  = h[node * D + lane];
    float hv = x > 0.0f ? x : expm1f(x);   // jax.nn.elu
    h[node * D + lane] = hv;
    // y_j = fc_b[j] + sum_d h_d * fc_w[j, d]   (lane = j)
    float acc = fc_b[lane];
#pragma unroll
    for (int dd = 0; dd < D; ++dd) {
        float hd = __shfl(hv, dd, 64);
        acc = fmaf(hd, fc_w[lane * D + dd], acc);
    }
    float t = tanhf(acc) * sem_attn[lane];
#pragma unroll
    for (int o = 32; o > 0; o >>= 1) t += __shfl_xor(t, o, 64);
    if (lane == 0) atomicAdd(&wsum[m_index], t);
}

// out = beta0*h_ap + beta1*h_sp  (h_ap lives in out, in-place)
__global__ void final_combine_kernel(float* __restrict__ out,
                                     const float* __restrict__ h_sp,
                                     const float* __restrict__ wsum,
                                     int n_elems) {
    int i = blockIdx.x * blockDim.x + threadIdx.x;
    if (i >= n_elems) return;
    float w0 = wsum[0] * (1.0f / N_PAPER);
    float w1 = wsum[1] * (1.0f / N_PAPER);
    float mx = fmaxf(w0, w1);
    float e0 = expf(w0 - mx), e1 = expf(w1 - mx);
    float inv = 1.0f / (e0 + e1);
    out[i] = (e0 * inv) * out[i] + (e1 * inv) * h_sp[i];
}

// ---------- launch ----------

extern "C" void kernel_launch(void* const* d_in, const int* in_sizes, int n_in,
                              void* d_out, int out_size, void* d_ws, size_t ws_size,
                              hipStream_t stream) {
    const float* feat_author = (const float*)d_in[0];
    const float* feat_subject= (const float*)d_in[1];
    const float* feat_paper  = (const float*)d_in[2];
    const int*   src_ap      = (const int*)d_in[3];
    const int*   dst_ap      = (const int*)d_in[4];
    const int*   src_sp      = (const int*)d_in[5];
    const int*   dst_sp      = (const int*)d_in[6];
    const float* attn_l_ap   = (const float*)d_in[7];
    const float* attn_r_ap   = (const float*)d_in[8];
    const float* attn_l_sp   = (const float*)d_in[9];
    const float* attn_r_sp   = (const float*)d_in[10];
    const float* fc_w        = (const float*)d_in[11];
    const float* fc_b        = (const float*)d_in[12];
    const float* sem_attn    = (const float*)d_in[13];

    float* out = (float*)d_out;   // accumulates h_ap, then final result

    // ---- workspace layout (zero-init region first) ----
    char* ws = (char*)d_ws;
    size_t off = 0;
    auto alloc = [&](size_t bytes) {
        size_t r = off;
        off = (off + bytes + 255) & ~(size_t)255;
        return r;
    };
    unsigned* emax_ap = (unsigned*)(ws + alloc(N_PAPER * 4));
    unsigned* emax_sp = (unsigned*)(ws + alloc(N_PAPER * 4));
    float*    denom_ap= (float*)(ws + alloc(N_PAPER * 4));
    float*    denom_sp= (float*)(ws + alloc(N_PAPER * 4));
    float*    wsum    = (float*)(ws + alloc(2 * 4));
    float*    h_sp    = (float*)(ws + alloc((size_t)N_PAPER * D * 4));
    size_t zero_bytes = off;          // everything above must start at 0
    float*    el_ap   = (float*)(ws + alloc(N_AUTHOR * 4));
    float*    er_ap   = (float*)(ws + alloc(N_PAPER * 4));
    float*    el_sp   = (float*)(ws + alloc(N_SUBJECT * 4));
    float*    er_sp   = (float*)(ws + alloc(N_PAPER * 4));
    float*    ee_ap   = (float*)(ws + alloc((size_t)NEDGE * 4));
    float*    ee_sp   = (float*)(ws + alloc((size_t)NEDGE * 4));
    (void)ws_size; (void)in_sizes; (void)n_in;

    hipMemsetAsync(d_ws, 0, zero_bytes, stream);
    hipMemsetAsync(d_out, 0, (size_t)out_size * 4, stream);

    const int B = 256;

    // node logits
    dot_rows_kernel<<<(N_AUTHOR + 3) / 4, B, 0, stream>>>(feat_author, attn_l_ap, el_ap, N_AUTHOR);
    dot_rows_kernel<<<(N_PAPER  + 3) / 4, B, 0, stream>>>(feat_paper,  attn_r_ap, er_ap, N_PAPER);
    dot_rows_kernel<<<(N_SUBJECT+ 3) / 4, B, 0, stream>>>(feat_subject,attn_l_sp, el_sp, N_SUBJECT);
    dot_rows_kernel<<<(N_PAPER  + 3) / 4, B, 0, stream>>>(feat_paper,  attn_r_sp, er_sp, N_PAPER);

    // edge softmax: max
    int egrid = (NEDGE + B - 1) / B;
    edge_max_kernel<<<egrid, B, 0, stream>>>(src_ap, dst_ap, el_ap, er_ap, emax_ap);
    edge_max_kernel<<<egrid, B, 0, stream>>>(src_sp, dst_sp, el_sp, er_sp, emax_sp);

    // edge softmax: exp + denom
    edge_expsum_kernel<<<egrid, B, 0, stream>>>(src_ap, dst_ap, el_ap, er_ap, emax_ap, ee_ap, denom_ap);
    edge_expsum_kernel<<<egrid, B, 0, stream>>>(src_sp, dst_sp, el_sp, er_sp, emax_sp, ee_sp, denom_sp);

    // weighted aggregation (wave per edge)
    int agrid = (NEDGE + 3) / 4;
    edge_aggregate_kernel<<<agrid, B, 0, stream>>>(src_ap, dst_ap, feat_author,  ee_ap, denom_ap, out);
    edge_aggregate_kernel<<<agrid, B, 0, stream>>>(src_sp, dst_sp, feat_subject, ee_sp, denom_sp, h_sp);

    // elu + semantic attention logits
    int ngrid = (N_PAPER + 3) / 4;
    elu_semantic_kernel<<<ngrid, B, 0, stream>>>(out,  fc_w, fc_b, sem_attn, wsum, 0, N_PAPER);
    elu_semantic_kernel<<<ngrid, B, 0, stream>>>(h_sp, fc_w, fc_b, sem_attn, wsum, 1, N_PAPER);

    // softmax over 2 metapaths + blend
    int n_elems = N_PAPER * D;
    final_combine_kernel<<<(n_elems + B - 1) / B, B, 0, stream>>>(out, h_sp, wsum, n_elems);
}

// Round 2
// 1056.682 us; speedup vs baseline: 3.2282x; 3.2282x over previous
//
#include <hip/hip_runtime.h>
#include <math.h>

#define N_AUTHOR 200000
#define N_SUBJECT 50000
#define N_PAPER 100000
#define NEDGE 1000000
#define D 64
#define NEG_SLOPE 0.01f

// ---------- helpers ----------

__device__ __forceinline__ unsigned enc_f32(float f) {
    unsigned b = __float_as_uint(f);
    return (b & 0x80000000u) ? ~b : (b | 0x80000000u);
}
__device__ __forceinline__ float dec_f32(unsigned e) {
    unsigned b = (e & 0x80000000u) ? (e ^ 0x80000000u) : ~e;
    return __uint_as_float(b);
}

// ---------- kernels ----------

// out[row] = dot(feat[row, :], vec)   (wave per row, lane per feature)
__global__ void dot_rows_kernel(const float* __restrict__ feat,
                                const float* __restrict__ vec,
                                float* __restrict__ out, int n) {
    int row  = blockIdx.x * 4 + (threadIdx.x >> 6);
    int lane = threadIdx.x & 63;
    if (row >= n) return;
    float v = feat[row * D + lane] * vec[lane];
#pragma unroll
    for (int o = 32; o > 0; o >>= 1) v += __shfl_xor(v, o, 64);
    if (lane == 0) out[row] = v;
}

// segment-max of leakyrelu(el[src]+er[dst]) by dst, via encoded atomicMax
__global__ void edge_max_kernel(const int* __restrict__ src,
                                const int* __restrict__ dst,
                                const float* __restrict__ el,
                                const float* __restrict__ er,
                                unsigned* __restrict__ emax) {
    int i = blockIdx.x * blockDim.x + threadIdx.x;
    if (i >= NEDGE) return;
    int d = dst[i];
    float e = el[src[i]] + er[d];
    e = e > 0.0f ? e : NEG_SLOPE * e;
    atomicMax(&emax[d], enc_f32(e));
}

// ee = exp(e - emax[dst]); denom[dst] += ee; store ee
__global__ void edge_expsum_kernel(const int* __restrict__ src,
                                   const int* __restrict__ dst,
                                   const float* __restrict__ el,
                                   const float* __restrict__ er,
                                   const unsigned* __restrict__ emax,
                                   float* __restrict__ ee,
                                   float* __restrict__ denom) {
    int i = blockIdx.x * blockDim.x + threadIdx.x;
    if (i >= NEDGE) return;
    int d = dst[i];
    float e = el[src[i]] + er[d];
    e = e > 0.0f ? e : NEG_SLOPE * e;
    float m = dec_f32(emax[d]);
    float x = expf(e - m);
    ee[i] = x;
    atomicAdd(&denom[d], x);
}

// wave per edge: accum[dst, :] += (ee/denom[dst]) * feat_src[src, :]
__global__ void edge_aggregate_kernel(const int* __restrict__ src,
                                      const int* __restrict__ dst,
                                      const float* __restrict__ feat_src,
                                      const float* __restrict__ ee,
                                      const float* __restrict__ denom,
                                      float* __restrict__ accum) {
    int e    = blockIdx.x * 4 + (threadIdx.x >> 6);
    int lane = threadIdx.x & 63;
    if (e >= NEDGE) return;
    int s = src[e], d = dst[e];
    float a = ee[e] / denom[d];
    atomicAdd(&accum[d * D + lane], a * feat_src[s * D + lane]);
}

// grid-stride, wave per node: h = elu(accum) in-place;
// block-accumulate tanh(h @ fc_w.T + fc_b) @ sem_attn, ONE atomic per block.
__global__ void elu_semantic_kernel(float* __restrict__ h,
                                    const float* __restrict__ fc_w,
                                    const float* __restrict__ fc_b,
                                    const float* __restrict__ sem_attn,
                                    float* __restrict__ wsum,
                                    int m_index, int n) {
    __shared__ float red[4];
    int wid  = threadIdx.x >> 6;
    int lane = threadIdx.x & 63;

    // hoist loop-invariant weights into registers (row `lane` of fc_w)
    float fw[D];
#pragma unroll
    for (int dd = 0; dd < D; ++dd) fw[dd] = fc_w[lane * D + dd];
    float fb = fc_b[lane];
    float sa = sem_attn[lane];

    float tacc = 0.0f;
    for (int node = blockIdx.x * 4 + wid; node < n; node += gridDim.x * 4) {
        float x  = h[node * D + lane];
        float hv = x > 0.0f ? x : expm1f(x);   // jax.nn.elu
        h[node * D + lane] = hv;
        float acc = fb;
#pragma unroll
        for (int dd = 0; dd < D; ++dd) {
            float hd = __shfl(hv, dd, 64);
            acc = fmaf(hd, fw[dd], acc);
        }
        float t = tanhf(acc) * sa;
#pragma unroll
        for (int o = 32; o > 0; o >>= 1) t += __shfl_xor(t, o, 64);
        tacc += t;                              // same value in all lanes
    }
    if (lane == 0) red[wid] = tacc;
    __syncthreads();
    if (threadIdx.x == 0) {
        float s = red[0] + red[1] + red[2] + red[3];
        atomicAdd(&wsum[m_index], s);
    }
}

// out = beta0*h_ap + beta1*h_sp  (h_ap lives in out, in-place)
__global__ void final_combine_kernel(float* __restrict__ out,
                                     const float* __restrict__ h_sp,
                                     const float* __restrict__ wsum,
                                     int n_elems) {
    int i = blockIdx.x * blockDim.x + threadIdx.x;
    if (i >= n_elems) return;
    float w0 = wsum[0] * (1.0f / N_PAPER);
    float w1 = wsum[1] * (1.0f / N_PAPER);
    float mx = fmaxf(w0, w1);
    float e0 = expf(w0 - mx), e1 = expf(w1 - mx);
    float inv = 1.0f / (e0 + e1);
    out[i] = (e0 * inv) * out[i] + (e1 * inv) * h_sp[i];
}

// ---------- launch ----------

extern "C" void kernel_launch(void* const* d_in, const int* in_sizes, int n_in,
                              void* d_out, int out_size, void* d_ws, size_t ws_size,
                              hipStream_t stream) {
    const float* feat_author = (const float*)d_in[0];
    const float* feat_subject= (const float*)d_in[1];
    const float* feat_paper  = (const float*)d_in[2];
    const int*   src_ap      = (const int*)d_in[3];
    const int*   dst_ap      = (const int*)d_in[4];
    const int*   src_sp      = (const int*)d_in[5];
    const int*   dst_sp      = (const int*)d_in[6];
    const float* attn_l_ap   = (const float*)d_in[7];
    const float* attn_r_ap   = (const float*)d_in[8];
    const float* attn_l_sp   = (const float*)d_in[9];
    const float* attn_r_sp   = (const float*)d_in[10];
    const float* fc_w        = (const float*)d_in[11];
    const float* fc_b        = (const float*)d_in[12];
    const float* sem_attn    = (const float*)d_in[13];

    float* out = (float*)d_out;   // accumulates h_ap, then final result

    // ---- workspace layout (zero-init region first) ----
    char* ws = (char*)d_ws;
    size_t off = 0;
    auto alloc = [&](size_t bytes) {
        size_t r = off;
        off = (off + bytes + 255) & ~(size_t)255;
        return r;
    };
    unsigned* emax_ap = (unsigned*)(ws + alloc(N_PAPER * 4));
    unsigned* emax_sp = (unsigned*)(ws + alloc(N_PAPER * 4));
    float*    denom_ap= (float*)(ws + alloc(N_PAPER * 4));
    float*    denom_sp= (float*)(ws + alloc(N_PAPER * 4));
    float*    wsum    = (float*)(ws + alloc(2 * 4));
    float*    h_sp    = (float*)(ws + alloc((size_t)N_PAPER * D * 4));
    size_t zero_bytes = off;          // everything above must start at 0
    float*    el_ap   = (float*)(ws + alloc(N_AUTHOR * 4));
    float*    er_ap   = (float*)(ws + alloc(N_PAPER * 4));
    float*    el_sp   = (float*)(ws + alloc(N_SUBJECT * 4));
    float*    er_sp   = (float*)(ws + alloc(N_PAPER * 4));
    float*    ee_ap   = (float*)(ws + alloc((size_t)NEDGE * 4));
    float*    ee_sp   = (float*)(ws + alloc((size_t)NEDGE * 4));
    (void)ws_size; (void)in_sizes; (void)n_in;

    hipMemsetAsync(d_ws, 0, zero_bytes, stream);
    hipMemsetAsync(d_out, 0, (size_t)out_size * 4, stream);

    const int B = 256;

    // node logits
    dot_rows_kernel<<<(N_AUTHOR + 3) / 4, B, 0, stream>>>(feat_author, attn_l_ap, el_ap, N_AUTHOR);
    dot_rows_kernel<<<(N_PAPER  + 3) / 4, B, 0, stream>>>(feat_paper,  attn_r_ap, er_ap, N_PAPER);
    dot_rows_kernel<<<(N_SUBJECT+ 3) / 4, B, 0, stream>>>(feat_subject,attn_l_sp, el_sp, N_SUBJECT);
    dot_rows_kernel<<<(N_PAPER  + 3) / 4, B, 0, stream>>>(feat_paper,  attn_r_sp, er_sp, N_PAPER);

    // edge softmax: max
    int egrid = (NEDGE + B - 1) / B;
    edge_max_kernel<<<egrid, B, 0, stream>>>(src_ap, dst_ap, el_ap, er_ap, emax_ap);
    edge_max_kernel<<<egrid, B, 0, stream>>>(src_sp, dst_sp, el_sp, er_sp, emax_sp);

    // edge softmax: exp + denom
    edge_expsum_kernel<<<egrid, B, 0, stream>>>(src_ap, dst_ap, el_ap, er_ap, emax_ap, ee_ap, denom_ap);
    edge_expsum_kernel<<<egrid, B, 0, stream>>>(src_sp, dst_sp, el_sp, er_sp, emax_sp, ee_sp, denom_sp);

    // weighted aggregation (wave per edge)
    int agrid = (NEDGE + 3) / 4;
    edge_aggregate_kernel<<<agrid, B, 0, stream>>>(src_ap, dst_ap, feat_author,  ee_ap, denom_ap, out);
    edge_aggregate_kernel<<<agrid, B, 0, stream>>>(src_sp, dst_sp, feat_subject, ee_sp, denom_sp, h_sp);

    // elu + semantic attention logits (grid-stride, one atomic per block)
    const int SEM_BLOCKS = 2048;
    elu_semantic_kernel<<<SEM_BLOCKS, B, 0, stream>>>(out,  fc_w, fc_b, sem_attn, wsum, 0, N_PAPER);
    elu_semantic_kernel<<<SEM_BLOCKS, B, 0, stream>>>(h_sp, fc_w, fc_b, sem_attn, wsum, 1, N_PAPER);

    // softmax over 2 metapaths + blend
    int n_elems = N_PAPER * D;
    final_combine_kernel<<<(n_elems + B - 1) / B, B, 0, stream>>>(out, h_sp, wsum, n_elems);
}

// Round 3
// 862.148 us; speedup vs baseline: 3.9566x; 1.2256x over previous
//
#include <hip/hip_runtime.h>
#include <math.h>

#define N_AUTHOR 200000
#define N_SUBJECT 50000
#define N_PAPER 100000
#define NEDGE 1000000
#define D 64
#define NEG_SLOPE 0.01f

#define CHUNK 1024
#define NCHUNK ((N_PAPER + CHUNK - 1) / CHUNK)   // 98

// ---------- kernels ----------

// out[row] = dot(feat[row, :], vec)   (wave per row, lane per feature)
__global__ void dot_rows_kernel(const float* __restrict__ feat,
                                const float* __restrict__ vec,
                                float* __restrict__ out, int n) {
    int row  = blockIdx.x * 4 + (threadIdx.x >> 6);
    int lane = threadIdx.x & 63;
    if (row >= n) return;
    float v = feat[row * D + lane] * vec[lane];
#pragma unroll
    for (int o = 32; o > 0; o >>= 1) v += __shfl_xor(v, o, 64);
    if (lane == 0) out[row] = v;
}

// count[dst]++ over all edges
__global__ void hist_kernel(const int* __restrict__ dst, int* __restrict__ count) {
    int i = blockIdx.x * blockDim.x + threadIdx.x;
    if (i >= NEDGE) return;
    atomicAdd(&count[dst[i]], 1);
}

// per-chunk sums (chunk = 1024 counts, block = 256 threads x 4 elems)
__global__ void chunk_sum_kernel(const int* __restrict__ count, int* __restrict__ psum) {
    __shared__ int red[4];
    int base = blockIdx.x * CHUNK;
    int t = threadIdx.x;
    int s = 0;
#pragma unroll
    for (int j = 0; j < 4; ++j) {
        int idx = base + t * 4 + j;
        if (idx < N_PAPER) s += count[idx];
    }
#pragma unroll
    for (int o = 32; o > 0; o >>= 1) s += __shfl_xor(s, o, 64);
    if ((t & 63) == 0) red[t >> 6] = s;
    __syncthreads();
    if (t == 0) psum[blockIdx.x] = red[0] + red[1] + red[2] + red[3];
}

// exclusive scan of the NCHUNK partials (tiny: single thread loop)
__global__ void scan_partials_kernel(int* __restrict__ psum) {
    if (threadIdx.x == 0 && blockIdx.x == 0) {
        int run = 0;
        for (int i = 0; i < NCHUNK; ++i) {
            int v = psum[i];
            psum[i] = run;
            run += v;
        }
    }
}

// intra-chunk exclusive scan + chunk offset -> row_ptr, cursor
__global__ void chunk_scan_kernel(const int* __restrict__ count,
                                  const int* __restrict__ psum,
                                  int* __restrict__ row_ptr,
                                  int* __restrict__ cursor) {
    __shared__ int ts[256];
    int base = blockIdx.x * CHUNK;
    int t = threadIdx.x;
    int loc[4];
    int s = 0;
#pragma unroll
    for (int j = 0; j < 4; ++j) {
        int idx = base + t * 4 + j;
        loc[j] = (idx < N_PAPER) ? count[idx] : 0;
        s += loc[j];
    }
    ts[t] = s;
    __syncthreads();
    // Hillis-Steele inclusive scan over 256 thread-sums
    for (int off = 1; off < 256; off <<= 1) {
        int v = (t >= off) ? ts[t - off] : 0;
        __syncthreads();
        ts[t] += v;
        __syncthreads();
    }
    int ex = (t ? ts[t - 1] : 0) + psum[blockIdx.x];
#pragma unroll
    for (int j = 0; j < 4; ++j) {
        int idx = base + t * 4 + j;
        if (idx < N_PAPER) {
            row_ptr[idx] = ex;
            cursor[idx]  = ex;
            ex += loc[j];
        }
    }
    if (blockIdx.x == 0 && t == 0) row_ptr[N_PAPER] = NEDGE;
}

// bucket-scatter edges by dst: store (src, leakyrelu(el[src]+er[dst]))
__global__ void scatter_kernel(const int* __restrict__ src,
                               const int* __restrict__ dst,
                               const float* __restrict__ el,
                               const float* __restrict__ er,
                               int* __restrict__ cursor,
                               int* __restrict__ ss,
                               float* __restrict__ se) {
    int i = blockIdx.x * blockDim.x + threadIdx.x;
    if (i >= NEDGE) return;
    int d = dst[i], s = src[i];
    float e = el[s] + er[d];
    e = e > 0.0f ? e : NEG_SLOPE * e;
    int pos = atomicAdd(&cursor[d], 1);
    ss[pos] = s;
    se[pos] = e;
}

// wave per destination node: softmax over its edges + weighted gather-sum.
// Atomic-free; one coalesced 256B store per node.
__global__ void node_gat_kernel(const int* __restrict__ row_ptr,
                                const int* __restrict__ ss,
                                const float* __restrict__ se,
                                const float* __restrict__ feat_src,
                                float* __restrict__ h) {
    int node = blockIdx.x * 4 + (threadIdx.x >> 6);
    int lane = threadIdx.x & 63;
    if (node >= N_PAPER) return;
    int start = row_ptr[node], end = row_ptr[node + 1];

    // segment max (lane-strided)
    float m = -1e30f;
    for (int i = start + lane; i < end; i += 64) m = fmaxf(m, se[i]);
#pragma unroll
    for (int o = 32; o > 0; o >>= 1) m = fmaxf(m, __shfl_xor(m, o, 64));

    // segment sum of exp (lane-strided)
    float sden = 0.0f;
    for (int i = start + lane; i < end; i += 64) sden += expf(se[i] - m);
#pragma unroll
    for (int o = 32; o > 0; o >>= 1) sden += __shfl_xor(sden, o, 64);

    // weighted aggregation: lane = feature, scalar loop over edges
    float acc = 0.0f;
    for (int i = start; i < end; ++i) {
        float a = expf(se[i] - m);
        int s = ss[i];
        acc = fmaf(a, feat_src[(size_t)s * D + lane], acc);
    }
    h[(size_t)node * D + lane] = (end > start) ? (acc / sden) : 0.0f;
}

// grid-stride, wave per node: h = elu(accum) in-place;
// block-accumulate tanh(h @ fc_w.T + fc_b) @ sem_attn, ONE atomic per block.
__global__ void elu_semantic_kernel(float* __restrict__ h,
                                    const float* __restrict__ fc_w,
                                    const float* __restrict__ fc_b,
                                    const float* __restrict__ sem_attn,
                                    float* __restrict__ wsum,
                                    int m_index, int n) {
    __shared__ float red[4];
    int wid  = threadIdx.x >> 6;
    int lane = threadIdx.x & 63;

    float fw[D];
#pragma unroll
    for (int dd = 0; dd < D; ++dd) fw[dd] = fc_w[lane * D + dd];
    float fb = fc_b[lane];
    float sa = sem_attn[lane];

    float tacc = 0.0f;
    for (int node = blockIdx.x * 4 + wid; node < n; node += gridDim.x * 4) {
        float x  = h[node * D + lane];
        float hv = x > 0.0f ? x : expm1f(x);   // jax.nn.elu
        h[node * D + lane] = hv;
        float acc = fb;
#pragma unroll
        for (int dd = 0; dd < D; ++dd) {
            float hd = __shfl(hv, dd, 64);
            acc = fmaf(hd, fw[dd], acc);
        }
        float t = tanhf(acc) * sa;
#pragma unroll
        for (int o = 32; o > 0; o >>= 1) t += __shfl_xor(t, o, 64);
        tacc += t;
    }
    if (lane == 0) red[wid] = tacc;
    __syncthreads();
    if (threadIdx.x == 0) {
        float s = red[0] + red[1] + red[2] + red[3];
        atomicAdd(&wsum[m_index], s);
    }
}

// out = beta0*h_ap + beta1*h_sp  (h_ap lives in out, in-place)
__global__ void final_combine_kernel(float* __restrict__ out,
                                     const float* __restrict__ h_sp,
                                     const float* __restrict__ wsum,
                                     int n_elems) {
    int i = blockIdx.x * blockDim.x + threadIdx.x;
    if (i >= n_elems) return;
    float w0 = wsum[0] * (1.0f / N_PAPER);
    float w1 = wsum[1] * (1.0f / N_PAPER);
    float mx = fmaxf(w0, w1);
    float e0 = expf(w0 - mx), e1 = expf(w1 - mx);
    float inv = 1.0f / (e0 + e1);
    out[i] = (e0 * inv) * out[i] + (e1 * inv) * h_sp[i];
}

// ---------- launch ----------

extern "C" void kernel_launch(void* const* d_in, const int* in_sizes, int n_in,
                              void* d_out, int out_size, void* d_ws, size_t ws_size,
                              hipStream_t stream) {
    const float* feat_author = (const float*)d_in[0];
    const float* feat_subject= (const float*)d_in[1];
    const float* feat_paper  = (const float*)d_in[2];
    const int*   src_ap      = (const int*)d_in[3];
    const int*   dst_ap      = (const int*)d_in[4];
    const int*   src_sp      = (const int*)d_in[5];
    const int*   dst_sp      = (const int*)d_in[6];
    const float* attn_l_ap   = (const float*)d_in[7];
    const float* attn_r_ap   = (const float*)d_in[8];
    const float* attn_l_sp   = (const float*)d_in[9];
    const float* attn_r_sp   = (const float*)d_in[10];
    const float* fc_w        = (const float*)d_in[11];
    const float* fc_b        = (const float*)d_in[12];
    const float* sem_attn    = (const float*)d_in[13];

    float* out = (float*)d_out;   // h_ap accumulates here, then final result

    // ---- workspace layout (zero-init region first) ----
    char* ws = (char*)d_ws;
    size_t off = 0;
    auto alloc = [&](size_t bytes) {
        size_t r = off;
        off = (off + bytes + 255) & ~(size_t)255;
        return r;
    };
    int*   count_ap = (int*)(ws + alloc(N_PAPER * 4));
    int*   count_sp = (int*)(ws + alloc(N_PAPER * 4));
    float* wsum     = (float*)(ws + alloc(2 * 4));
    size_t zero_bytes = off;          // everything above must start at 0
    int*   row_ptr_ap = (int*)(ws + alloc((N_PAPER + 1) * 4));
    int*   cursor_ap  = (int*)(ws + alloc(N_PAPER * 4));
    int*   row_ptr_sp = (int*)(ws + alloc((N_PAPER + 1) * 4));
    int*   cursor_sp  = (int*)(ws + alloc(N_PAPER * 4));
    int*   psum_ap    = (int*)(ws + alloc(NCHUNK * 4));
    int*   psum_sp    = (int*)(ws + alloc(NCHUNK * 4));
    float* el_ap      = (float*)(ws + alloc(N_AUTHOR * 4));
    float* er_ap      = (float*)(ws + alloc(N_PAPER * 4));
    float* el_sp      = (float*)(ws + alloc(N_SUBJECT * 4));
    float* er_sp      = (float*)(ws + alloc(N_PAPER * 4));
    int*   ss_ap      = (int*)(ws + alloc((size_t)NEDGE * 4));
    float* se_ap      = (float*)(ws + alloc((size_t)NEDGE * 4));
    int*   ss_sp      = (int*)(ws + alloc((size_t)NEDGE * 4));
    float* se_sp      = (float*)(ws + alloc((size_t)NEDGE * 4));
    float* h_sp       = (float*)(ws + alloc((size_t)N_PAPER * D * 4));
    (void)ws_size; (void)in_sizes; (void)n_in;

    hipMemsetAsync(d_ws, 0, zero_bytes, stream);

    const int B = 256;
    int egrid = (NEDGE + B - 1) / B;

    // node logits
    dot_rows_kernel<<<(N_AUTHOR + 3) / 4, B, 0, stream>>>(feat_author, attn_l_ap, el_ap, N_AUTHOR);
    dot_rows_kernel<<<(N_PAPER  + 3) / 4, B, 0, stream>>>(feat_paper,  attn_r_ap, er_ap, N_PAPER);
    dot_rows_kernel<<<(N_SUBJECT+ 3) / 4, B, 0, stream>>>(feat_subject,attn_l_sp, el_sp, N_SUBJECT);
    dot_rows_kernel<<<(N_PAPER  + 3) / 4, B, 0, stream>>>(feat_paper,  attn_r_sp, er_sp, N_PAPER);

    // CSR build: histogram
    hist_kernel<<<egrid, B, 0, stream>>>(dst_ap, count_ap);
    hist_kernel<<<egrid, B, 0, stream>>>(dst_sp, count_sp);

    // CSR build: 3-pass exclusive scan
    chunk_sum_kernel<<<NCHUNK, B, 0, stream>>>(count_ap, psum_ap);
    chunk_sum_kernel<<<NCHUNK, B, 0, stream>>>(count_sp, psum_sp);
    scan_partials_kernel<<<1, 64, 0, stream>>>(psum_ap);
    scan_partials_kernel<<<1, 64, 0, stream>>>(psum_sp);
    chunk_scan_kernel<<<NCHUNK, B, 0, stream>>>(count_ap, psum_ap, row_ptr_ap, cursor_ap);
    chunk_scan_kernel<<<NCHUNK, B, 0, stream>>>(count_sp, psum_sp, row_ptr_sp, cursor_sp);

    // CSR build: bucket scatter (computes edge logits once)
    scatter_kernel<<<egrid, B, 0, stream>>>(src_ap, dst_ap, el_ap, er_ap, cursor_ap, ss_ap, se_ap);
    scatter_kernel<<<egrid, B, 0, stream>>>(src_sp, dst_sp, el_sp, er_sp, cursor_sp, ss_sp, se_sp);

    // atomic-free GAT per node
    int ngrid = (N_PAPER + 3) / 4;
    node_gat_kernel<<<ngrid, B, 0, stream>>>(row_ptr_ap, ss_ap, se_ap, feat_author,  out);
    node_gat_kernel<<<ngrid, B, 0, stream>>>(row_ptr_sp, ss_sp, se_sp, feat_subject, h_sp);

    // elu + semantic attention logits (grid-stride, one atomic per block)
    const int SEM_BLOCKS = 2048;
    elu_semantic_kernel<<<SEM_BLOCKS, B, 0, stream>>>(out,  fc_w, fc_b, sem_attn, wsum, 0, N_PAPER);
    elu_semantic_kernel<<<SEM_BLOCKS, B, 0, stream>>>(h_sp, fc_w, fc_b, sem_attn, wsum, 1, N_PAPER);

    // softmax over 2 metapaths + blend
    int n_elems = N_PAPER * D;
    final_combine_kernel<<<(n_elems + B - 1) / B, B, 0, stream>>>(out, h_sp, wsum, n_elems);
}

// Round 4
// 647.111 us; speedup vs baseline: 5.2714x; 1.3323x over previous
//
#include <hip/hip_runtime.h>
#include <math.h>

#define N_AUTHOR 200000
#define N_SUBJECT 50000
#define N_PAPER 100000
#define NEDGE 1000000
#define D 64
#define NEG_SLOPE 0.01f

#define NSLOT (2 * N_PAPER)                     // 200000 (ap nodes then sp nodes)
#define CHUNK 1024
#define NCHUNK ((NSLOT + CHUNK - 1) / CHUNK)    // 196

// ---------- kernels ----------

// All four node-logit dot products in one pass; paper rows read once.
__global__ void dots_fused_kernel(const float* __restrict__ fa,
                                  const float* __restrict__ fs,
                                  const float* __restrict__ fp,
                                  const float* __restrict__ al_ap,
                                  const float* __restrict__ ar_ap,
                                  const float* __restrict__ al_sp,
                                  const float* __restrict__ ar_sp,
                                  float* __restrict__ el_ap,
                                  float* __restrict__ el_sp,
                                  float* __restrict__ er_ap,
                                  float* __restrict__ er_sp) {
    int row  = blockIdx.x * 4 + (threadIdx.x >> 6);
    int lane = threadIdx.x & 63;
    if (row < N_AUTHOR) {
        float v = fa[(size_t)row * D + lane] * al_ap[lane];
#pragma unroll
        for (int o = 32; o > 0; o >>= 1) v += __shfl_xor(v, o, 64);
        if (lane == 0) el_ap[row] = v;
    } else if (row < N_AUTHOR + N_SUBJECT) {
        int r = row - N_AUTHOR;
        float v = fs[(size_t)r * D + lane] * al_sp[lane];
#pragma unroll
        for (int o = 32; o > 0; o >>= 1) v += __shfl_xor(v, o, 64);
        if (lane == 0) el_sp[r] = v;
    } else if (row < N_AUTHOR + N_SUBJECT + N_PAPER) {
        int r = row - (N_AUTHOR + N_SUBJECT);
        float f  = fp[(size_t)r * D + lane];
        float v0 = f * ar_ap[lane];
        float v1 = f * ar_sp[lane];
#pragma unroll
        for (int o = 32; o > 0; o >>= 1) {
            v0 += __shfl_xor(v0, o, 64);
            v1 += __shfl_xor(v1, o, 64);
        }
        if (lane == 0) { er_ap[r] = v0; er_sp[r] = v1; }
    }
}

// histogram over both edge lists into concatenated count[NSLOT]
__global__ void hist2_kernel(const int* __restrict__ dst_ap,
                             const int* __restrict__ dst_sp,
                             int* __restrict__ count) {
    int i = blockIdx.x * blockDim.x + threadIdx.x;
    if (i < NEDGE)            atomicAdd(&count[dst_ap[i]], 1);
    else if (i < 2 * NEDGE)   atomicAdd(&count[N_PAPER + dst_sp[i - NEDGE]], 1);
}

// per-chunk sums (chunk = 1024 counts, block = 256 threads x 4 elems)
__global__ void chunk_sum_kernel(const int* __restrict__ count, int* __restrict__ psum) {
    __shared__ int red[4];
    int base = blockIdx.x * CHUNK;
    int t = threadIdx.x;
    int s = 0;
#pragma unroll
    for (int j = 0; j < 4; ++j) {
        int idx = base + t * 4 + j;
        if (idx < NSLOT) s += count[idx];
    }
#pragma unroll
    for (int o = 32; o > 0; o >>= 1) s += __shfl_xor(s, o, 64);
    if ((t & 63) == 0) red[t >> 6] = s;
    __syncthreads();
    if (t == 0) psum[blockIdx.x] = red[0] + red[1] + red[2] + red[3];
}

// parallel exclusive scan of NCHUNK (=196) partials, one 256-thread block
__global__ void scan_partials_kernel(int* __restrict__ psum) {
    __shared__ int buf[256];
    int t = threadIdx.x;
    buf[t] = (t < NCHUNK) ? psum[t] : 0;
    __syncthreads();
    for (int off = 1; off < 256; off <<= 1) {
        int v = (t >= off) ? buf[t - off] : 0;
        __syncthreads();
        buf[t] += v;
        __syncthreads();
    }
    if (t < NCHUNK) psum[t] = t ? buf[t - 1] : 0;
}

// intra-chunk exclusive scan + chunk offset -> row_ptr, cursor
__global__ void chunk_scan_kernel(const int* __restrict__ count,
                                  const int* __restrict__ psum,
                                  int* __restrict__ row_ptr,
                                  int* __restrict__ cursor) {
    __shared__ int ts[256];
    int base = blockIdx.x * CHUNK;
    int t = threadIdx.x;
    int loc[4];
    int s = 0;
#pragma unroll
    for (int j = 0; j < 4; ++j) {
        int idx = base + t * 4 + j;
        loc[j] = (idx < NSLOT) ? count[idx] : 0;
        s += loc[j];
    }
    ts[t] = s;
    __syncthreads();
    for (int off = 1; off < 256; off <<= 1) {
        int v = (t >= off) ? ts[t - off] : 0;
        __syncthreads();
        ts[t] += v;
        __syncthreads();
    }
    int ex = (t ? ts[t - 1] : 0) + psum[blockIdx.x];
#pragma unroll
    for (int j = 0; j < 4; ++j) {
        int idx = base + t * 4 + j;
        if (idx < NSLOT) {
            row_ptr[idx] = ex;
            cursor[idx]  = ex;
            ex += loc[j];
        }
    }
    if (blockIdx.x == 0 && t == 0) row_ptr[NSLOT] = 2 * NEDGE;
}

// bucket-scatter both edge lists: rec[pos] = (src, leakyrelu(el[src]+er[dst]))
__global__ void scatter2_kernel(const int* __restrict__ src_ap,
                                const int* __restrict__ dst_ap,
                                const int* __restrict__ src_sp,
                                const int* __restrict__ dst_sp,
                                const float* __restrict__ el_ap,
                                const float* __restrict__ er_ap,
                                const float* __restrict__ el_sp,
                                const float* __restrict__ er_sp,
                                int* __restrict__ cursor,
                                int2* __restrict__ rec) {
    int i = blockIdx.x * blockDim.x + threadIdx.x;
    if (i >= 2 * NEDGE) return;
    int s, dslot; float e;
    if (i < NEDGE) {
        s = src_ap[i];
        int d = dst_ap[i];
        e = el_ap[s] + er_ap[d];
        dslot = d;
    } else {
        int j = i - NEDGE;
        s = src_sp[j];
        int d = dst_sp[j];
        e = el_sp[s] + er_sp[d];
        dslot = N_PAPER + d;
    }
    e = e > 0.0f ? e : NEG_SLOPE * e;
    int pos = atomicAdd(&cursor[dslot], 1);
    rec[pos] = make_int2(s, __float_as_int(e));
}

// Grid-stride, wave per node-slot: softmax + gather-agg + ELU + store h
// + fused semantic matvec (fc_w staged in padded LDS) + wsum accumulation.
__global__ void node_gat_fused_kernel(const int* __restrict__ row_ptr,
                                      const int2* __restrict__ rec,
                                      const float* __restrict__ feat_author,
                                      const float* __restrict__ feat_subject,
                                      float* __restrict__ h_ap,   // = d_out
                                      float* __restrict__ h_sp,
                                      const float* __restrict__ fc_w,
                                      const float* __restrict__ fc_b,
                                      const float* __restrict__ sem_attn,
                                      float* __restrict__ wsum) {
    __shared__ float fwl[D * 65];   // fwl[j*65+dd] = fc_w[j][dd], pad breaks bank conflicts
    __shared__ float red[8];
    int wid  = threadIdx.x >> 6;
    int lane = threadIdx.x & 63;

    for (int idx = threadIdx.x; idx < D * D; idx += 256)
        fwl[(idx >> 6) * 65 + (idx & 63)] = fc_w[idx];
    __syncthreads();

    float fb = fc_b[lane];
    float sa = sem_attn[lane];
    float tacc0 = 0.0f, tacc1 = 0.0f;

    for (int slot = blockIdx.x * 4 + wid; slot < NSLOT; slot += gridDim.x * 4) {
        int mp = slot >= N_PAPER;
        const float* feat = mp ? feat_subject : feat_author;
        int start = row_ptr[slot], end = row_ptr[slot + 1];

        // segment max (lane-strided over the bucket)
        float m = -1e30f;
        for (int i = start + lane; i < end; i += 64)
            m = fmaxf(m, __int_as_float(rec[i].y));
#pragma unroll
        for (int o = 32; o > 0; o >>= 1) m = fmaxf(m, __shfl_xor(m, o, 64));

        // one pass: exp (once per edge) + denom + weighted gather-agg
        float sdenl = 0.0f, accA = 0.0f, accB = 0.0f;
        for (int c = start; c < end; c += 64) {
            int rem = end - c; if (rem > 64) rem = 64;
            float wreg = 0.0f; int sreg = 0;
            if (lane < rem) {
                int2 r = rec[c + lane];
                wreg = expf(__int_as_float(r.y) - m);
                sreg = r.x;
                sdenl += wreg;
            }
            int j = 0;
            for (; j + 2 <= rem; j += 2) {
                float w0 = __shfl(wreg, j, 64),  w1 = __shfl(wreg, j + 1, 64);
                int   s0 = __shfl(sreg, j, 64);  int s1 = __shfl(sreg, j + 1, 64);
                accA = fmaf(w0, feat[(size_t)s0 * D + lane], accA);
                accB = fmaf(w1, feat[(size_t)s1 * D + lane], accB);
            }
            if (j < rem) {
                float w0 = __shfl(wreg, j, 64);
                int   s0 = __shfl(sreg, j, 64);
                accA = fmaf(w0, feat[(size_t)s0 * D + lane], accA);
            }
        }
        float sden = sdenl;
#pragma unroll
        for (int o = 32; o > 0; o >>= 1) sden += __shfl_xor(sden, o, 64);

        float hpre = (end > start) ? ((accA + accB) / sden) : 0.0f;
        float hv = hpre > 0.0f ? hpre : expm1f(hpre);   // ELU

        float* h = mp ? (h_sp + (size_t)(slot - N_PAPER) * D)
                      : (h_ap + (size_t)slot * D);
        h[lane] = hv;

        // semantic matvec: y_lane = fb + sum_dd hv_dd * fc_w[lane][dd]
        float acc2 = fb;
#pragma unroll
        for (int dd = 0; dd < D; ++dd)
            acc2 = fmaf(__shfl(hv, dd, 64), fwl[lane * 65 + dd], acc2);
        float t = tanhf(acc2) * sa;
#pragma unroll
        for (int o = 32; o > 0; o >>= 1) t += __shfl_xor(t, o, 64);
        if (mp) tacc1 += t; else tacc0 += t;
    }

    if (lane == 0) { red[wid] = tacc0; red[4 + wid] = tacc1; }
    __syncthreads();
    if (threadIdx.x == 0) atomicAdd(&wsum[0], red[0] + red[1] + red[2] + red[3]);
    if (threadIdx.x == 1) atomicAdd(&wsum[1], red[4] + red[5] + red[6] + red[7]);
}

// out = beta0*h_ap + beta1*h_sp  (h_ap lives in out, in-place)
__global__ void final_combine_kernel(float* __restrict__ out,
                                     const float* __restrict__ h_sp,
                                     const float* __restrict__ wsum,
                                     int n_elems) {
    int i = blockIdx.x * blockDim.x + threadIdx.x;
    if (i >= n_elems) return;
    float w0 = wsum[0] * (1.0f / N_PAPER);
    float w1 = wsum[1] * (1.0f / N_PAPER);
    float mx = fmaxf(w0, w1);
    float e0 = expf(w0 - mx), e1 = expf(w1 - mx);
    float inv = 1.0f / (e0 + e1);
    out[i] = (e0 * inv) * out[i] + (e1 * inv) * h_sp[i];
}

// ---------- launch ----------

extern "C" void kernel_launch(void* const* d_in, const int* in_sizes, int n_in,
                              void* d_out, int out_size, void* d_ws, size_t ws_size,
                              hipStream_t stream) {
    const float* feat_author = (const float*)d_in[0];
    const float* feat_subject= (const float*)d_in[1];
    const float* feat_paper  = (const float*)d_in[2];
    const int*   src_ap      = (const int*)d_in[3];
    const int*   dst_ap      = (const int*)d_in[4];
    const int*   src_sp      = (const int*)d_in[5];
    const int*   dst_sp      = (const int*)d_in[6];
    const float* attn_l_ap   = (const float*)d_in[7];
    const float* attn_r_ap   = (const float*)d_in[8];
    const float* attn_l_sp   = (const float*)d_in[9];
    const float* attn_r_sp   = (const float*)d_in[10];
    const float* fc_w        = (const float*)d_in[11];
    const float* fc_b        = (const float*)d_in[12];
    const float* sem_attn    = (const float*)d_in[13];

    float* out = (float*)d_out;   // h_ap lives here, then final result

    // ---- workspace layout (zero-init region first) ----
    char* ws = (char*)d_ws;
    size_t off = 0;
    auto alloc = [&](size_t bytes) {
        size_t r = off;
        off = (off + bytes + 255) & ~(size_t)255;
        return r;
    };
    int*   count   = (int*)(ws + alloc((size_t)NSLOT * 4));
    float* wsum    = (float*)(ws + alloc(2 * 4));
    size_t zero_bytes = off;          // everything above must start at 0
    int*   row_ptr = (int*)(ws + alloc((size_t)(NSLOT + 1) * 4));
    int*   cursor  = (int*)(ws + alloc((size_t)NSLOT * 4));
    int*   psum    = (int*)(ws + alloc((size_t)NCHUNK * 4));
    float* el_ap   = (float*)(ws + alloc((size_t)N_AUTHOR * 4));
    float* er_ap   = (float*)(ws + alloc((size_t)N_PAPER * 4));
    float* el_sp   = (float*)(ws + alloc((size_t)N_SUBJECT * 4));
    float* er_sp   = (float*)(ws + alloc((size_t)N_PAPER * 4));
    int2*  rec     = (int2*)(ws + alloc((size_t)(2 * NEDGE) * 8));
    float* h_sp    = (float*)(ws + alloc((size_t)N_PAPER * D * 4));
    (void)ws_size; (void)in_sizes; (void)n_in;

    hipMemsetAsync(d_ws, 0, zero_bytes, stream);

    const int B = 256;

    // node logits (one fused pass; papers read once)
    int drows = N_AUTHOR + N_SUBJECT + N_PAPER;           // 350000
    dots_fused_kernel<<<(drows + 3) / 4, B, 0, stream>>>(
        feat_author, feat_subject, feat_paper,
        attn_l_ap, attn_r_ap, attn_l_sp, attn_r_sp,
        el_ap, el_sp, er_ap, er_sp);

    // CSR build over concatenated slot space
    int e2grid = (2 * NEDGE + B - 1) / B;
    hist2_kernel<<<e2grid, B, 0, stream>>>(dst_ap, dst_sp, count);
    chunk_sum_kernel<<<NCHUNK, B, 0, stream>>>(count, psum);
    scan_partials_kernel<<<1, 256, 0, stream>>>(psum);
    chunk_scan_kernel<<<NCHUNK, B, 0, stream>>>(count, psum, row_ptr, cursor);
    scatter2_kernel<<<e2grid, B, 0, stream>>>(src_ap, dst_ap, src_sp, dst_sp,
                                              el_ap, er_ap, el_sp, er_sp,
                                              cursor, rec);

    // fused GAT + ELU + semantic matvec (grid-stride, 2048 blocks)
    node_gat_fused_kernel<<<2048, B, 0, stream>>>(row_ptr, rec,
                                                  feat_author, feat_subject,
                                                  out, h_sp,
                                                  fc_w, fc_b, sem_attn, wsum);

    // softmax over 2 metapaths + blend
    int n_elems = N_PAPER * D;
    final_combine_kernel<<<(n_elems + B - 1) / B, B, 0, stream>>>(out, h_sp, wsum, n_elems);
}

// Round 5
// 635.856 us; speedup vs baseline: 5.3647x; 1.0177x over previous
//
#include <hip/hip_runtime.h>
#include <math.h>

#define N_AUTHOR 200000
#define N_SUBJECT 50000
#define N_PAPER 100000
#define NEDGE 1000000
#define D 64
#define NEG_SLOPE 0.01f

#define NSLOT (2 * N_PAPER)                     // 200000 (ap nodes then sp nodes)
#define CHUNK 1024
#define NCHUNK ((NSLOT + CHUNK - 1) / CHUNK)    // 196

// ---------- kernels ----------

// All four node-logit dot products in one pass; paper rows read once.
__global__ void dots_fused_kernel(const float* __restrict__ fa,
                                  const float* __restrict__ fs,
                                  const float* __restrict__ fp,
                                  const float* __restrict__ al_ap,
                                  const float* __restrict__ ar_ap,
                                  const float* __restrict__ al_sp,
                                  const float* __restrict__ ar_sp,
                                  float* __restrict__ el_ap,
                                  float* __restrict__ el_sp,
                                  float* __restrict__ er_ap,
                                  float* __restrict__ er_sp) {
    int row  = blockIdx.x * 4 + (threadIdx.x >> 6);
    int lane = threadIdx.x & 63;
    if (row < N_AUTHOR) {
        float v = fa[(size_t)row * D + lane] * al_ap[lane];
#pragma unroll
        for (int o = 32; o > 0; o >>= 1) v += __shfl_xor(v, o, 64);
        if (lane == 0) el_ap[row] = v;
    } else if (row < N_AUTHOR + N_SUBJECT) {
        int r = row - N_AUTHOR;
        float v = fs[(size_t)r * D + lane] * al_sp[lane];
#pragma unroll
        for (int o = 32; o > 0; o >>= 1) v += __shfl_xor(v, o, 64);
        if (lane == 0) el_sp[r] = v;
    } else if (row < N_AUTHOR + N_SUBJECT + N_PAPER) {
        int r = row - (N_AUTHOR + N_SUBJECT);
        float f  = fp[(size_t)r * D + lane];
        float v0 = f * ar_ap[lane];
        float v1 = f * ar_sp[lane];
#pragma unroll
        for (int o = 32; o > 0; o >>= 1) {
            v0 += __shfl_xor(v0, o, 64);
            v1 += __shfl_xor(v1, o, 64);
        }
        if (lane == 0) { er_ap[r] = v0; er_sp[r] = v1; }
    }
}

// histogram over both edge lists into concatenated count[NSLOT]
__global__ void hist2_kernel(const int* __restrict__ dst_ap,
                             const int* __restrict__ dst_sp,
                             int* __restrict__ count) {
    int i = blockIdx.x * blockDim.x + threadIdx.x;
    if (i < NEDGE)            atomicAdd(&count[dst_ap[i]], 1);
    else if (i < 2 * NEDGE)   atomicAdd(&count[N_PAPER + dst_sp[i - NEDGE]], 1);
}

// per-chunk sums (chunk = 1024 counts, block = 256 threads x 4 elems)
__global__ void chunk_sum_kernel(const int* __restrict__ count, int* __restrict__ psum) {
    __shared__ int red[4];
    int base = blockIdx.x * CHUNK;
    int t = threadIdx.x;
    int s = 0;
#pragma unroll
    for (int j = 0; j < 4; ++j) {
        int idx = base + t * 4 + j;
        if (idx < NSLOT) s += count[idx];
    }
#pragma unroll
    for (int o = 32; o > 0; o >>= 1) s += __shfl_xor(s, o, 64);
    if ((t & 63) == 0) red[t >> 6] = s;
    __syncthreads();
    if (t == 0) psum[blockIdx.x] = red[0] + red[1] + red[2] + red[3];
}

// parallel exclusive scan of NCHUNK (=196) partials, one 256-thread block
__global__ void scan_partials_kernel(int* __restrict__ psum) {
    __shared__ int buf[256];
    int t = threadIdx.x;
    buf[t] = (t < NCHUNK) ? psum[t] : 0;
    __syncthreads();
    for (int off = 1; off < 256; off <<= 1) {
        int v = (t >= off) ? buf[t - off] : 0;
        __syncthreads();
        buf[t] += v;
        __syncthreads();
    }
    if (t < NCHUNK) psum[t] = t ? buf[t - 1] : 0;
}

// intra-chunk exclusive scan + chunk offset -> row_ptr, cursor
__global__ void chunk_scan_kernel(const int* __restrict__ count,
                                  const int* __restrict__ psum,
                                  int* __restrict__ row_ptr,
                                  int* __restrict__ cursor) {
    __shared__ int ts[256];
    int base = blockIdx.x * CHUNK;
    int t = threadIdx.x;
    int loc[4];
    int s = 0;
#pragma unroll
    for (int j = 0; j < 4; ++j) {
        int idx = base + t * 4 + j;
        loc[j] = (idx < NSLOT) ? count[idx] : 0;
        s += loc[j];
    }
    ts[t] = s;
    __syncthreads();
    for (int off = 1; off < 256; off <<= 1) {
        int v = (t >= off) ? ts[t - off] : 0;
        __syncthreads();
        ts[t] += v;
        __syncthreads();
    }
    int ex = (t ? ts[t - 1] : 0) + psum[blockIdx.x];
#pragma unroll
    for (int j = 0; j < 4; ++j) {
        int idx = base + t * 4 + j;
        if (idx < NSLOT) {
            row_ptr[idx] = ex;
            cursor[idx]  = ex;
            ex += loc[j];
        }
    }
    if (blockIdx.x == 0 && t == 0) row_ptr[NSLOT] = 2 * NEDGE;
}

// bucket-scatter both edge lists (2 edges/thread for MLP):
// rec[pos] = (src, leakyrelu(el[src]+er[dst]))
__global__ void scatter2_kernel(const int* __restrict__ src_ap,
                                const int* __restrict__ dst_ap,
                                const int* __restrict__ src_sp,
                                const int* __restrict__ dst_sp,
                                const float* __restrict__ el_ap,
                                const float* __restrict__ er_ap,
                                const float* __restrict__ el_sp,
                                const float* __restrict__ er_sp,
                                int* __restrict__ cursor,
                                int2* __restrict__ rec) {
    int i0 = (blockIdx.x * blockDim.x + threadIdx.x) * 2;
#pragma unroll
    for (int k = 0; k < 2; ++k) {
        int i = i0 + k;
        if (i >= 2 * NEDGE) break;
        int s, dslot; float e;
        if (i < NEDGE) {
            s = src_ap[i];
            int d = dst_ap[i];
            e = el_ap[s] + er_ap[d];
            dslot = d;
        } else {
            int j = i - NEDGE;
            s = src_sp[j];
            int d = dst_sp[j];
            e = el_sp[s] + er_sp[d];
            dslot = N_PAPER + d;
        }
        e = e > 0.0f ? e : NEG_SLOPE * e;
        int pos = atomicAdd(&cursor[dslot], 1);
        rec[pos] = make_int2(s, __float_as_int(e));
    }
}

// Grid-stride, wave per node-slot: softmax + gather-agg + ELU + store h
// + fused semantic matvec (fc_w staged in padded LDS) + wsum accumulation.
__global__ void node_gat_fused_kernel(const int* __restrict__ row_ptr,
                                      const int2* __restrict__ rec,
                                      const float* __restrict__ feat_author,
                                      const float* __restrict__ feat_subject,
                                      float* __restrict__ h_ap,   // = d_out
                                      float* __restrict__ h_sp,
                                      const float* __restrict__ fc_w,
                                      const float* __restrict__ fc_b,
                                      const float* __restrict__ sem_attn,
                                      float* __restrict__ wsum) {
    __shared__ float fwl[D * 65];   // fwl[j*65+dd] = fc_w[j][dd]
    __shared__ float red[8];
    int wid  = threadIdx.x >> 6;
    int lane = threadIdx.x & 63;

    for (int idx = threadIdx.x; idx < D * D; idx += 256)
        fwl[(idx >> 6) * 65 + (idx & 63)] = fc_w[idx];
    __syncthreads();

    float fb = fc_b[lane];
    float sa = sem_attn[lane];
    float tacc0 = 0.0f, tacc1 = 0.0f;

    for (int slot = blockIdx.x * 4 + wid; slot < NSLOT; slot += gridDim.x * 4) {
        int mp = slot >= N_PAPER;
        const float* feat = mp ? feat_subject : feat_author;
        int start = row_ptr[slot], end = row_ptr[slot + 1];
        int len = end - start;

        float hpre;
        if (len == 0) {
            hpre = 0.0f;
        } else if (len <= 64) {
            // ---- fast path: whole bucket register-resident, one rec read ----
            int2 r = make_int2(0, 0xff800000);          // e = -inf for idle lanes
            if (lane < len) r = rec[start + lane];
            float ev = __int_as_float(r.y);
            float m = ev;
#pragma unroll
            for (int o = 32; o > 0; o >>= 1) m = fmaxf(m, __shfl_xor(m, o, 64));
            float w = (lane < len) ? __expf(ev - m) : 0.0f;
            float sden = w;
#pragma unroll
            for (int o = 32; o > 0; o >>= 1) sden += __shfl_xor(sden, o, 64);

            float a0 = 0.0f, a1 = 0.0f, a2 = 0.0f, a3 = 0.0f;
            int j = 0;
            for (; j + 4 <= len; j += 4) {
                float w0 = __shfl(w, j, 64),   w1 = __shfl(w, j + 1, 64);
                float w2 = __shfl(w, j + 2, 64), w3 = __shfl(w, j + 3, 64);
                int   s0 = __shfl(r.x, j, 64),   s1 = __shfl(r.x, j + 1, 64);
                int   s2 = __shfl(r.x, j + 2, 64), s3 = __shfl(r.x, j + 3, 64);
                a0 = fmaf(w0, feat[(size_t)s0 * D + lane], a0);
                a1 = fmaf(w1, feat[(size_t)s1 * D + lane], a1);
                a2 = fmaf(w2, feat[(size_t)s2 * D + lane], a2);
                a3 = fmaf(w3, feat[(size_t)s3 * D + lane], a3);
            }
            for (; j < len; ++j) {
                float w0 = __shfl(w, j, 64);
                int   s0 = __shfl(r.x, j, 64);
                a0 = fmaf(w0, feat[(size_t)s0 * D + lane], a0);
            }
            hpre = ((a0 + a1) + (a2 + a3)) / sden;
        } else {
            // ---- generic path (degree > 64; statistically never) ----
            float m = -1e30f;
            for (int i = start + lane; i < end; i += 64)
                m = fmaxf(m, __int_as_float(rec[i].y));
#pragma unroll
            for (int o = 32; o > 0; o >>= 1) m = fmaxf(m, __shfl_xor(m, o, 64));
            float sdenl = 0.0f, accA = 0.0f, accB = 0.0f;
            for (int c = start; c < end; c += 64) {
                int rem = end - c; if (rem > 64) rem = 64;
                float wreg = 0.0f; int sreg = 0;
                if (lane < rem) {
                    int2 r = rec[c + lane];
                    wreg = __expf(__int_as_float(r.y) - m);
                    sreg = r.x;
                    sdenl += wreg;
                }
                int j = 0;
                for (; j + 2 <= rem; j += 2) {
                    float w0 = __shfl(wreg, j, 64), w1 = __shfl(wreg, j + 1, 64);
                    int   s0 = __shfl(sreg, j, 64), s1 = __shfl(sreg, j + 1, 64);
                    accA = fmaf(w0, feat[(size_t)s0 * D + lane], accA);
                    accB = fmaf(w1, feat[(size_t)s1 * D + lane], accB);
                }
                if (j < rem) {
                    float w0 = __shfl(wreg, j, 64);
                    int   s0 = __shfl(sreg, j, 64);
                    accA = fmaf(w0, feat[(size_t)s0 * D + lane], accA);
                }
            }
            float sden = sdenl;
#pragma unroll
            for (int o = 32; o > 0; o >>= 1) sden += __shfl_xor(sden, o, 64);
            hpre = (accA + accB) / sden;
        }

        float hv = hpre > 0.0f ? hpre : expm1f(hpre);   // ELU

        float* h = mp ? (h_sp + (size_t)(slot - N_PAPER) * D)
                      : (h_ap + (size_t)slot * D);
        h[lane] = hv;

        // semantic matvec: y_lane = fb + sum_dd hv_dd * fc_w[lane][dd]
        float acc2 = fb;
#pragma unroll
        for (int dd = 0; dd < D; ++dd)
            acc2 = fmaf(__shfl(hv, dd, 64), fwl[lane * 65 + dd], acc2);
        float t = tanhf(acc2) * sa;
#pragma unroll
        for (int o = 32; o > 0; o >>= 1) t += __shfl_xor(t, o, 64);
        if (mp) tacc1 += t; else tacc0 += t;
    }

    if (lane == 0) { red[wid] = tacc0; red[4 + wid] = tacc1; }
    __syncthreads();
    if (threadIdx.x == 0) atomicAdd(&wsum[0], red[0] + red[1] + red[2] + red[3]);
    if (threadIdx.x == 1) atomicAdd(&wsum[1], red[4] + red[5] + red[6] + red[7]);
}

// out = beta0*out + beta1*h_sp, float4 vectorized (n_elems % 4 == 0)
__global__ void final_combine_kernel(float4* __restrict__ out,
                                     const float4* __restrict__ h_sp,
                                     const float* __restrict__ wsum,
                                     int n_vec4) {
    int i = blockIdx.x * blockDim.x + threadIdx.x;
    if (i >= n_vec4) return;
    float w0 = wsum[0] * (1.0f / N_PAPER);
    float w1 = wsum[1] * (1.0f / N_PAPER);
    float mx = fmaxf(w0, w1);
    float e0 = __expf(w0 - mx), e1 = __expf(w1 - mx);
    float inv = 1.0f / (e0 + e1);
    float b0 = e0 * inv, b1 = e1 * inv;
    float4 a = out[i], b = h_sp[i];
    out[i] = make_float4(b0 * a.x + b1 * b.x, b0 * a.y + b1 * b.y,
                         b0 * a.z + b1 * b.z, b0 * a.w + b1 * b.w);
}

// ---------- launch ----------

extern "C" void kernel_launch(void* const* d_in, const int* in_sizes, int n_in,
                              void* d_out, int out_size, void* d_ws, size_t ws_size,
                              hipStream_t stream) {
    const float* feat_author = (const float*)d_in[0];
    const float* feat_subject= (const float*)d_in[1];
    const float* feat_paper  = (const float*)d_in[2];
    const int*   src_ap      = (const int*)d_in[3];
    const int*   dst_ap      = (const int*)d_in[4];
    const int*   src_sp      = (const int*)d_in[5];
    const int*   dst_sp      = (const int*)d_in[6];
    const float* attn_l_ap   = (const float*)d_in[7];
    const float* attn_r_ap   = (const float*)d_in[8];
    const float* attn_l_sp   = (const float*)d_in[9];
    const float* attn_r_sp   = (const float*)d_in[10];
    const float* fc_w        = (const float*)d_in[11];
    const float* fc_b        = (const float*)d_in[12];
    const float* sem_attn    = (const float*)d_in[13];

    float* out = (float*)d_out;   // h_ap lives here, then final result

    // ---- workspace layout (zero-init region first) ----
    char* ws = (char*)d_ws;
    size_t off = 0;
    auto alloc = [&](size_t bytes) {
        size_t r = off;
        off = (off + bytes + 255) & ~(size_t)255;
        return r;
    };
    int*   count   = (int*)(ws + alloc((size_t)NSLOT * 4));
    float* wsum    = (float*)(ws + alloc(2 * 4));
    size_t zero_bytes = off;          // everything above must start at 0
    int*   row_ptr = (int*)(ws + alloc((size_t)(NSLOT + 1) * 4));
    int*   cursor  = (int*)(ws + alloc((size_t)NSLOT * 4));
    int*   psum    = (int*)(ws + alloc((size_t)NCHUNK * 4));
    float* el_ap   = (float*)(ws + alloc((size_t)N_AUTHOR * 4));
    float* er_ap   = (float*)(ws + alloc((size_t)N_PAPER * 4));
    float* el_sp   = (float*)(ws + alloc((size_t)N_SUBJECT * 4));
    float* er_sp   = (float*)(ws + alloc((size_t)N_PAPER * 4));
    int2*  rec     = (int2*)(ws + alloc((size_t)(2 * NEDGE) * 8));
    float* h_sp    = (float*)(ws + alloc((size_t)N_PAPER * D * 4));
    (void)ws_size; (void)in_sizes; (void)n_in;

    hipMemsetAsync(d_ws, 0, zero_bytes, stream);

    const int B = 256;

    // node logits (one fused pass; papers read once)
    int drows = N_AUTHOR + N_SUBJECT + N_PAPER;           // 350000
    dots_fused_kernel<<<(drows + 3) / 4, B, 0, stream>>>(
        feat_author, feat_subject, feat_paper,
        attn_l_ap, attn_r_ap, attn_l_sp, attn_r_sp,
        el_ap, el_sp, er_ap, er_sp);

    // CSR build over concatenated slot space
    int e2grid = (2 * NEDGE + B - 1) / B;
    hist2_kernel<<<e2grid, B, 0, stream>>>(dst_ap, dst_sp, count);
    chunk_sum_kernel<<<NCHUNK, B, 0, stream>>>(count, psum);
    scan_partials_kernel<<<1, 256, 0, stream>>>(psum);
    chunk_scan_kernel<<<NCHUNK, B, 0, stream>>>(count, psum, row_ptr, cursor);
    int s2grid = (2 * NEDGE + 2 * B - 1) / (2 * B);
    scatter2_kernel<<<s2grid, B, 0, stream>>>(src_ap, dst_ap, src_sp, dst_sp,
                                              el_ap, er_ap, el_sp, er_sp,
                                              cursor, rec);

    // fused GAT + ELU + semantic matvec (grid-stride, 2048 blocks)
    node_gat_fused_kernel<<<2048, B, 0, stream>>>(row_ptr, rec,
                                                  feat_author, feat_subject,
                                                  out, h_sp,
                                                  fc_w, fc_b, sem_attn, wsum);

    // softmax over 2 metapaths + blend
    int n_vec4 = N_PAPER * D / 4;
    final_combine_kernel<<<(n_vec4 + B - 1) / B, B, 0, stream>>>(
        (float4*)out, (const float4*)h_sp, wsum, n_vec4);
}

// Round 6
// 581.838 us; speedup vs baseline: 5.8628x; 1.0928x over previous
//
#include <hip/hip_runtime.h>
#include <math.h>

#define N_AUTHOR 200000
#define N_SUBJECT 50000
#define N_PAPER 100000
#define NEDGE 1000000
#define D 64
#define NEG_SLOPE 0.01f

#define NSLOT (2 * N_PAPER)                     // 200000 (ap nodes then sp nodes)
#define CHUNK 1024
#define NCHUNK ((NSLOT + CHUNK - 1) / CHUNK)    // 196
#define DROWS (N_AUTHOR + N_SUBJECT + N_PAPER)  // 350000

__device__ __forceinline__ float bcast(float v, int lane) {
    return __uint_as_float((unsigned)__builtin_amdgcn_readlane(__float_as_int(v), lane));
}
__device__ __forceinline__ int bcast_i(int v, int lane) {
    return __builtin_amdgcn_readlane(v, lane);
}
__device__ __forceinline__ float fast_tanh(float x) {
    x = fminf(15.0f, fmaxf(-15.0f, x));
    float ex = __expf(2.0f * x);
    return (ex - 1.0f) / (ex + 1.0f);
}

// ---------- kernels ----------

// Merged: node-logit dot products (blocks [0, nb_dots)) + dst histogram (rest).
__global__ void dots_hist_kernel(const float* __restrict__ fa,
                                 const float* __restrict__ fs,
                                 const float* __restrict__ fp,
                                 const float* __restrict__ al_ap,
                                 const float* __restrict__ ar_ap,
                                 const float* __restrict__ al_sp,
                                 const float* __restrict__ ar_sp,
                                 float* __restrict__ el_ap,
                                 float* __restrict__ el_sp,
                                 float* __restrict__ er_ap,
                                 float* __restrict__ er_sp,
                                 const int* __restrict__ dst_ap,
                                 const int* __restrict__ dst_sp,
                                 int* __restrict__ count,
                                 int nb_dots) {
    if ((int)blockIdx.x < nb_dots) {
        int row  = blockIdx.x * 4 + (threadIdx.x >> 6);
        int lane = threadIdx.x & 63;
        if (row < N_AUTHOR) {
            float v = fa[(size_t)row * D + lane] * al_ap[lane];
#pragma unroll
            for (int o = 32; o > 0; o >>= 1) v += __shfl_xor(v, o, 64);
            if (lane == 0) el_ap[row] = v;
        } else if (row < N_AUTHOR + N_SUBJECT) {
            int r = row - N_AUTHOR;
            float v = fs[(size_t)r * D + lane] * al_sp[lane];
#pragma unroll
            for (int o = 32; o > 0; o >>= 1) v += __shfl_xor(v, o, 64);
            if (lane == 0) el_sp[r] = v;
        } else if (row < DROWS) {
            int r = row - (N_AUTHOR + N_SUBJECT);
            float f  = fp[(size_t)r * D + lane];
            float v0 = f * ar_ap[lane];
            float v1 = f * ar_sp[lane];
#pragma unroll
            for (int o = 32; o > 0; o >>= 1) {
                v0 += __shfl_xor(v0, o, 64);
                v1 += __shfl_xor(v1, o, 64);
            }
            if (lane == 0) { er_ap[r] = v0; er_sp[r] = v1; }
        }
    } else {
        int i = (blockIdx.x - nb_dots) * blockDim.x + threadIdx.x;
        if (i < NEDGE)          atomicAdd(&count[dst_ap[i]], 1);
        else if (i < 2 * NEDGE) atomicAdd(&count[N_PAPER + dst_sp[i - NEDGE]], 1);
    }
}

// per-chunk sums (chunk = 1024 counts, block = 256 threads x 4 elems)
__global__ void chunk_sum_kernel(const int* __restrict__ count, int* __restrict__ psum) {
    __shared__ int red[4];
    int base = blockIdx.x * CHUNK;
    int t = threadIdx.x;
    int s = 0;
#pragma unroll
    for (int j = 0; j < 4; ++j) {
        int idx = base + t * 4 + j;
        if (idx < NSLOT) s += count[idx];
    }
#pragma unroll
    for (int o = 32; o > 0; o >>= 1) s += __shfl_xor(s, o, 64);
    if ((t & 63) == 0) red[t >> 6] = s;
    __syncthreads();
    if (t == 0) psum[blockIdx.x] = red[0] + red[1] + red[2] + red[3];
}

// parallel exclusive scan of NCHUNK (=196) partials, one 256-thread block
__global__ void scan_partials_kernel(int* __restrict__ psum) {
    __shared__ int buf[256];
    int t = threadIdx.x;
    buf[t] = (t < NCHUNK) ? psum[t] : 0;
    __syncthreads();
    for (int off = 1; off < 256; off <<= 1) {
        int v = (t >= off) ? buf[t - off] : 0;
        __syncthreads();
        buf[t] += v;
        __syncthreads();
    }
    if (t < NCHUNK) psum[t] = t ? buf[t - 1] : 0;
}

// intra-chunk exclusive scan + chunk offset -> row_ptr, cursor
__global__ void chunk_scan_kernel(const int* __restrict__ count,
                                  const int* __restrict__ psum,
                                  int* __restrict__ row_ptr,
                                  int* __restrict__ cursor) {
    __shared__ int ts[256];
    int base = blockIdx.x * CHUNK;
    int t = threadIdx.x;
    int loc[4];
    int s = 0;
#pragma unroll
    for (int j = 0; j < 4; ++j) {
        int idx = base + t * 4 + j;
        loc[j] = (idx < NSLOT) ? count[idx] : 0;
        s += loc[j];
    }
    ts[t] = s;
    __syncthreads();
    for (int off = 1; off < 256; off <<= 1) {
        int v = (t >= off) ? ts[t - off] : 0;
        __syncthreads();
        ts[t] += v;
        __syncthreads();
    }
    int ex = (t ? ts[t - 1] : 0) + psum[blockIdx.x];
#pragma unroll
    for (int j = 0; j < 4; ++j) {
        int idx = base + t * 4 + j;
        if (idx < NSLOT) {
            row_ptr[idx] = ex;
            cursor[idx]  = ex;
            ex += loc[j];
        }
    }
    if (blockIdx.x == 0 && t == 0) row_ptr[NSLOT] = 2 * NEDGE;
}

// bucket-scatter both edge lists, 4 strided edges/thread:
// rec[pos] = (src, leakyrelu(el[src]+er[dst]))
__global__ void scatter2_kernel(const int* __restrict__ src_ap,
                                const int* __restrict__ dst_ap,
                                const int* __restrict__ src_sp,
                                const int* __restrict__ dst_sp,
                                const float* __restrict__ el_ap,
                                const float* __restrict__ er_ap,
                                const float* __restrict__ el_sp,
                                const float* __restrict__ er_sp,
                                int* __restrict__ cursor,
                                int2* __restrict__ rec) {
    const int nthreads = 2 * NEDGE / 4;   // 500000
    int tid = blockIdx.x * blockDim.x + threadIdx.x;
    if (tid >= nthreads) return;
#pragma unroll
    for (int k = 0; k < 4; ++k) {
        int i = tid + k * nthreads;       // coalesced per k
        int s, dslot; float e;
        if (i < NEDGE) {
            s = src_ap[i];
            int d = dst_ap[i];
            e = el_ap[s] + er_ap[d];
            dslot = d;
        } else {
            int j = i - NEDGE;
            s = src_sp[j];
            int d = dst_sp[j];
            e = el_sp[s] + er_sp[d];
            dslot = N_PAPER + d;
        }
        e = e > 0.0f ? e : NEG_SLOPE * e;
        int pos = atomicAdd(&cursor[dslot], 1);
        rec[pos] = make_int2(s, __float_as_int(e));
    }
}

// Grid-stride, wave per node-slot: softmax + gather-agg + ELU + store h
// + fused semantic matvec (fc_w row in VGPRs, readlane broadcasts — no DS ops).
__global__ void __launch_bounds__(256, 4)
node_gat_fused_kernel(const int* __restrict__ row_ptr,
                      const int2* __restrict__ rec,
                      const float* __restrict__ feat_author,
                      const float* __restrict__ feat_subject,
                      float* __restrict__ h_ap,   // = d_out
                      float* __restrict__ h_sp,
                      const float* __restrict__ fc_w,
                      const float* __restrict__ fc_b,
                      const float* __restrict__ sem_attn,
                      float* __restrict__ wsum) {
    __shared__ float red[8];
    int wid  = threadIdx.x >> 6;
    int lane = threadIdx.x & 63;

    // fc_w row `lane` in registers (static indexing only -> VGPRs)
    float fw[D];
    {
        const float4* fw4 = (const float4*)(fc_w + (size_t)lane * D);
#pragma unroll
        for (int k = 0; k < 16; ++k) {
            float4 v = fw4[k];
            fw[4 * k + 0] = v.x; fw[4 * k + 1] = v.y;
            fw[4 * k + 2] = v.z; fw[4 * k + 3] = v.w;
        }
    }
    float fb = fc_b[lane];
    float sa = sem_attn[lane];
    float tacc0 = 0.0f, tacc1 = 0.0f;

    for (int slot = blockIdx.x * 4 + wid; slot < NSLOT; slot += gridDim.x * 4) {
        int mp = slot >= N_PAPER;
        const float* feat = mp ? feat_subject : feat_author;
        int start = row_ptr[slot], end = row_ptr[slot + 1];
        int len = end - start;

        float hpre;
        if (len == 0) {
            hpre = 0.0f;
        } else if (len <= 64) {
            // ---- fast path: bucket register-resident, readlane broadcasts ----
            int2 r = make_int2(0, 0xff800000);          // e = -inf for idle lanes
            if (lane < len) r = rec[start + lane];
            float ev = __int_as_float(r.y);
            float m = ev;
#pragma unroll
            for (int o = 32; o > 0; o >>= 1) m = fmaxf(m, __shfl_xor(m, o, 64));
            float w = (lane < len) ? __expf(ev - m) : 0.0f;
            float sden = w;
#pragma unroll
            for (int o = 32; o > 0; o >>= 1) sden += __shfl_xor(sden, o, 64);

            float a0 = 0.0f, a1 = 0.0f, a2 = 0.0f, a3 = 0.0f;
            int j = 0;
            for (; j + 4 <= len; j += 4) {
                float w0 = bcast(w, j),     w1 = bcast(w, j + 1);
                float w2 = bcast(w, j + 2), w3 = bcast(w, j + 3);
                int   s0 = bcast_i(r.x, j),     s1 = bcast_i(r.x, j + 1);
                int   s2 = bcast_i(r.x, j + 2), s3 = bcast_i(r.x, j + 3);
                a0 = fmaf(w0, feat[(size_t)s0 * D + lane], a0);
                a1 = fmaf(w1, feat[(size_t)s1 * D + lane], a1);
                a2 = fmaf(w2, feat[(size_t)s2 * D + lane], a2);
                a3 = fmaf(w3, feat[(size_t)s3 * D + lane], a3);
            }
            for (; j < len; ++j) {
                float w0 = bcast(w, j);
                int   s0 = bcast_i(r.x, j);
                a0 = fmaf(w0, feat[(size_t)s0 * D + lane], a0);
            }
            hpre = ((a0 + a1) + (a2 + a3)) / sden;
        } else {
            // ---- generic path (degree > 64; statistically never) ----
            float m = -1e30f;
            for (int i = start + lane; i < end; i += 64)
                m = fmaxf(m, __int_as_float(rec[i].y));
#pragma unroll
            for (int o = 32; o > 0; o >>= 1) m = fmaxf(m, __shfl_xor(m, o, 64));
            float sdenl = 0.0f, accA = 0.0f, accB = 0.0f;
            for (int c = start; c < end; c += 64) {
                int rem = end - c; if (rem > 64) rem = 64;
                float wreg = 0.0f; int sreg = 0;
                if (lane < rem) {
                    int2 r = rec[c + lane];
                    wreg = __expf(__int_as_float(r.y) - m);
                    sreg = r.x;
                    sdenl += wreg;
                }
                int j = 0;
                for (; j + 2 <= rem; j += 2) {
                    float w0 = bcast(wreg, j), w1 = bcast(wreg, j + 1);
                    int   s0 = bcast_i(sreg, j), s1 = bcast_i(sreg, j + 1);
                    accA = fmaf(w0, feat[(size_t)s0 * D + lane], accA);
                    accB = fmaf(w1, feat[(size_t)s1 * D + lane], accB);
                }
                if (j < rem) {
                    float w0 = bcast(wreg, j);
                    int   s0 = bcast_i(sreg, j);
                    accA = fmaf(w0, feat[(size_t)s0 * D + lane], accA);
                }
            }
            float sden = sdenl;
#pragma unroll
            for (int o = 32; o > 0; o >>= 1) sden += __shfl_xor(sden, o, 64);
            hpre = (accA + accB) / sden;
        }

        float hv = hpre > 0.0f ? hpre : (__expf(hpre) - 1.0f);   // ELU

        float* h = mp ? (h_sp + (size_t)(slot - N_PAPER) * D)
                      : (h_ap + (size_t)slot * D);
        h[lane] = hv;

        // semantic matvec: y_lane = fb + sum_dd hv_dd * fw[dd]  (readlane, no DS)
        float acc2 = fb;
#pragma unroll
        for (int dd = 0; dd < D; ++dd)
            acc2 = fmaf(bcast(hv, dd), fw[dd], acc2);
        float t = fast_tanh(acc2) * sa;
#pragma unroll
        for (int o = 32; o > 0; o >>= 1) t += __shfl_xor(t, o, 64);
        if (mp) tacc1 += t; else tacc0 += t;
    }

    if (lane == 0) { red[wid] = tacc0; red[4 + wid] = tacc1; }
    __syncthreads();
    if (threadIdx.x == 0) atomicAdd(&wsum[0], red[0] + red[1] + red[2] + red[3]);
    if (threadIdx.x == 1) atomicAdd(&wsum[1], red[4] + red[5] + red[6] + red[7]);
}

// out = beta0*out + beta1*h_sp, float4 vectorized (n_elems % 4 == 0)
__global__ void final_combine_kernel(float4* __restrict__ out,
                                     const float4* __restrict__ h_sp,
                                     const float* __restrict__ wsum,
                                     int n_vec4) {
    int i = blockIdx.x * blockDim.x + threadIdx.x;
    if (i >= n_vec4) return;
    float w0 = wsum[0] * (1.0f / N_PAPER);
    float w1 = wsum[1] * (1.0f / N_PAPER);
    float mx = fmaxf(w0, w1);
    float e0 = __expf(w0 - mx), e1 = __expf(w1 - mx);
    float inv = 1.0f / (e0 + e1);
    float b0 = e0 * inv, b1 = e1 * inv;
    float4 a = out[i], b = h_sp[i];
    out[i] = make_float4(b0 * a.x + b1 * b.x, b0 * a.y + b1 * b.y,
                         b0 * a.z + b1 * b.z, b0 * a.w + b1 * b.w);
}

// ---------- launch ----------

extern "C" void kernel_launch(void* const* d_in, const int* in_sizes, int n_in,
                              void* d_out, int out_size, void* d_ws, size_t ws_size,
                              hipStream_t stream) {
    const float* feat_author = (const float*)d_in[0];
    const float* feat_subject= (const float*)d_in[1];
    const float* feat_paper  = (const float*)d_in[2];
    const int*   src_ap      = (const int*)d_in[3];
    const int*   dst_ap      = (const int*)d_in[4];
    const int*   src_sp      = (const int*)d_in[5];
    const int*   dst_sp      = (const int*)d_in[6];
    const float* attn_l_ap   = (const float*)d_in[7];
    const float* attn_r_ap   = (const float*)d_in[8];
    const float* attn_l_sp   = (const float*)d_in[9];
    const float* attn_r_sp   = (const float*)d_in[10];
    const float* fc_w        = (const float*)d_in[11];
    const float* fc_b        = (const float*)d_in[12];
    const float* sem_attn    = (const float*)d_in[13];

    float* out = (float*)d_out;   // h_ap lives here, then final result

    // ---- workspace layout (zero-init region first) ----
    char* ws = (char*)d_ws;
    size_t off = 0;
    auto alloc = [&](size_t bytes) {
        size_t r = off;
        off = (off + bytes + 255) & ~(size_t)255;
        return r;
    };
    int*   count   = (int*)(ws + alloc((size_t)NSLOT * 4));
    float* wsum    = (float*)(ws + alloc(2 * 4));
    size_t zero_bytes = off;          // everything above must start at 0
    int*   row_ptr = (int*)(ws + alloc((size_t)(NSLOT + 1) * 4));
    int*   cursor  = (int*)(ws + alloc((size_t)NSLOT * 4));
    int*   psum    = (int*)(ws + alloc((size_t)NCHUNK * 4));
    float* el_ap   = (float*)(ws + alloc((size_t)N_AUTHOR * 4));
    float* er_ap   = (float*)(ws + alloc((size_t)N_PAPER * 4));
    float* el_sp   = (float*)(ws + alloc((size_t)N_SUBJECT * 4));
    float* er_sp   = (float*)(ws + alloc((size_t)N_PAPER * 4));
    int2*  rec     = (int2*)(ws + alloc((size_t)(2 * NEDGE) * 8));
    float* h_sp    = (float*)(ws + alloc((size_t)N_PAPER * D * 4));
    (void)ws_size; (void)in_sizes; (void)n_in;

    hipMemsetAsync(d_ws, 0, zero_bytes, stream);

    const int B = 256;

    // node logits + histogram in one launch (independent work)
    int nb_dots = (DROWS + 3) / 4;                  // 87500
    int nb_hist = (2 * NEDGE + B - 1) / B;          // 7813
    dots_hist_kernel<<<nb_dots + nb_hist, B, 0, stream>>>(
        feat_author, feat_subject, feat_paper,
        attn_l_ap, attn_r_ap, attn_l_sp, attn_r_sp,
        el_ap, el_sp, er_ap, er_sp,
        dst_ap, dst_sp, count, nb_dots);

    // CSR build over concatenated slot space
    chunk_sum_kernel<<<NCHUNK, B, 0, stream>>>(count, psum);
    scan_partials_kernel<<<1, 256, 0, stream>>>(psum);
    chunk_scan_kernel<<<NCHUNK, B, 0, stream>>>(count, psum, row_ptr, cursor);
    int s2grid = (2 * NEDGE / 4 + B - 1) / B;
    scatter2_kernel<<<s2grid, B, 0, stream>>>(src_ap, dst_ap, src_sp, dst_sp,
                                              el_ap, er_ap, el_sp, er_sp,
                                              cursor, rec);

    // fused GAT + ELU + semantic matvec (grid-stride, 2048 blocks)
    node_gat_fused_kernel<<<2048, B, 0, stream>>>(row_ptr, rec,
                                                  feat_author, feat_subject,
                                                  out, h_sp,
                                                  fc_w, fc_b, sem_attn, wsum);

    // softmax over 2 metapaths + blend
    int n_vec4 = N_PAPER * D / 4;
    final_combine_kernel<<<(n_vec4 + B - 1) / B, B, 0, stream>>>(
        (float4*)out, (const float4*)h_sp, wsum, n_vec4);
}